// Round 17
// baseline (560.851 us; speedup 1.0000x reference)
//
#include <hip/hip_runtime.h>

typedef unsigned short ushort_t;
typedef __attribute__((ext_vector_type(8))) short short8;
typedef __attribute__((ext_vector_type(4))) float f32x4;

#define TOKENS  4096
#define H_DIM   1024
#define HFF_DIM 4096
#define NEXP    8

#define XCVT_BLOCKS  (TOKENS * H_DIM / 8 / 256)           // 2048 (256-thr)
#define W1CVT_BLOCKS (NEXP * HFF_DIM * H_DIM / 8 / 256)   // 16384 (256-thr)
#define W2CVT_BLOCKS (NEXP * H_DIM * HFF_DIM / 8 / 128)   // 32768 (128-thr filler)
#define G1_BLOCKS    (NEXP * 64 * 32)                     // 16384 (64 mt x 32 nt)
#define G2_BLOCKS    (NEXP * 64 * 8)                      // 4096  (64 mt x 8 nt)

// round-to-nearest-even f32 -> bf16
__device__ __forceinline__ ushort_t f2b(float f) {
    union { float f; unsigned u; } v; v.f = f;
    unsigned r = v.u + 0x7fffu + ((v.u >> 16) & 1u);
    return (ushort_t)(r >> 16);
}

__device__ __forceinline__ void cvt8(const float* __restrict__ src,
                                     ushort_t* __restrict__ dst, size_t i) {
    const float4* s = (const float4*)(src + i * 8);
    float4 a = s[0], b = s[1];
    ushort_t o[8];
    o[0] = f2b(a.x); o[1] = f2b(a.y); o[2] = f2b(a.z); o[3] = f2b(a.w);
    o[4] = f2b(b.x); o[5] = f2b(b.y); o[6] = f2b(b.z); o[7] = f2b(b.w);
    *(short8*)(dst + i * 8) = *(short8*)o;
}

// jax.nn.gelu default: approximate=True (tanh form)
__device__ __forceinline__ float gelu_tanh(float x) {
    float u = 0.7978845608028654f * (x + 0.044715f * x * x * x);
    return 0.5f * x * (1.0f + tanhf(u));
}

// async global->LDS, 16B per lane; LDS dest is wave-uniform base + lane*16
__device__ __forceinline__ void gload16(const ushort_t* g, ushort_t* l) {
    __builtin_amdgcn_global_load_lds(
        (const __attribute__((address_space(1))) unsigned int*)g,
        (__attribute__((address_space(3))) unsigned int*)l,
        16, 0, 0);
}

// ---------------- prep: x-cvt + routing + W1-cvt in ONE launch (R13/R15-verified) ----------------
__global__ void prep_kernel(const float* __restrict__ probs,
                            const int* __restrict__ idx,
                            const float* __restrict__ x,
                            ushort_t* __restrict__ xb,
                            const float* __restrict__ W1,
                            ushort_t* __restrict__ W1b,
                            int* __restrict__ count,
                            int* __restrict__ token_id,
                            float* __restrict__ gate) {
    const int wg = blockIdx.x;
    if (wg >= XCVT_BLOCKS) {
        cvt8(W1, W1b, (size_t)(wg - XCVT_BLOCKS) * 256 + threadIdx.x);
        return;
    }
    const int gid = wg * 256 + threadIdx.x;
    cvt8(x, xb, (size_t)gid);

    if (wg >= TOKENS / 256) return;           // only first 16 blocks route (full waves)
    const int t = gid;                        // < TOKENS
    const int lane = threadIdx.x & 63;

    const int i0 = idx[t * 2 + 0];
    const int i1 = idx[t * 2 + 1];
    const float p0 = probs[t * 2 + 0];
    const float p1 = probs[t * 2 + 1];
    const bool dup = (i0 == i1);
    const float q0 = dup ? fmaxf(p0, p1) : p0;

#pragma unroll
    for (int k = 0; k < 2; ++k) {
        const int want = (k == 0) ? i0 : (dup ? -1 : i1);
        const float p  = (k == 0) ? q0 : p1;
#pragma unroll
        for (int e = 0; e < NEXP; ++e) {
            unsigned long long m = __ballot(want == e);
            if (m == 0ull) continue;                       // wave-uniform
            if (want == e) {
                const int lead = __ffsll((long long)m) - 1;
                int base = 0;
                if (lane == lead) base = atomicAdd(&count[e], (int)__popcll(m));
                base = __shfl(base, lead);
                const int pos = base + (int)__popcll(m & ((1ull << lane) - 1ull));
                token_id[e * TOKENS + pos] = t;
                gate[e * TOKENS + pos] = p;
            }
        }
    }
}

// ---------------- f32 -> bf16 bulk convert (fallback path only) ----------------
__global__ void cvt_kernel(const float* __restrict__ src, ushort_t* __restrict__ dst, int n8) {
    int i = blockIdx.x * blockDim.x + threadIdx.x;
    if (i >= n8) return;
    cvt8(src, dst, (size_t)i);
}

// 64x128 tile, 2 waves/block (each wave = same 64x64 / 4x4-acc / 16-MFMA shape
// as the verified 128^2 kernel). Rationale: GEMMs measured latency-bound at
// 2 blocks/CU; halving the M-tile doubles independent load-chains per CU
// (m114 cross-block overlap) with zero change to per-wave code, atomics,
// or numerics. Staging: 12 gloads (A:4, B:8) split 6/6 across the 2 waves.

// ---------------- GEMM1 (+W2-cvt filler blocks) ----------------
__global__ __launch_bounds__(128) void gemm1_kernel(
        const ushort_t* __restrict__ xb, const ushort_t* __restrict__ W1b,
        const int* __restrict__ count, const int* __restrict__ token_id,
        ushort_t* __restrict__ h,
        const float* __restrict__ W2, ushort_t* __restrict__ W2b) {
    if (blockIdx.x >= G1_BLOCKS) {
        cvt8(W2, W2b, (size_t)(blockIdx.x - G1_BLOCKS) * 128 + threadIdx.x);
        return;
    }
    const int wg  = blockIdx.x;
    const int swz = (wg & 7) * (G1_BLOCKS / 8) + (wg >> 3);
    const int e   = swz >> 11;          // 64 mt * 32 nt = 2048 per expert
    const int rem = swz & 2047;
    const int mt  = rem >> 5;           // nt fastest: A-panel sharers consecutive
    const int nt  = rem & 31;

    const int cnt = count[e];
    if (mt * 64 >= cnt) return;
    int base = 0;
    for (int i = 0; i < e; ++i) base += count[i];

    __shared__ __align__(16) ushort_t As[64 * 32];
    __shared__ __align__(16) ushort_t Bs[128 * 32];

    const int tid = threadIdx.x;
    const int lane = tid & 63;
    const int wave = tid >> 6;          // 0,1

    const int r16 = lane >> 2;          // row within 16-row chunk
    const int sc  = (lane & 3) << 3;    // col in ushorts

    // per-wave staging: wave0 = A rows 0-63 (4 gloads) + B rows 0-31 (2);
    //                   wave1 = B rows 32-127 (6 gloads)
    const ushort_t* sp[6];
    ushort_t* ld[6];
    const ushort_t* Wbase = W1b + (size_t)e * HFF_DIM * H_DIM;
    if (wave == 0) {
#pragma unroll
        for (int g = 0; g < 4; ++g) {
            int ra = mt * 64 + g * 16 + r16;
            if (ra >= cnt) ra = cnt - 1;               // clamp: garbage rows unused
            const int tok = token_id[e * TOKENS + ra];
            sp[g] = xb + (size_t)tok * H_DIM + sc;
            ld[g] = &As[g * 512];
        }
#pragma unroll
        for (int g = 0; g < 2; ++g) {
            sp[4 + g] = Wbase + (size_t)(nt * 128 + g * 16 + r16) * H_DIM + sc;
            ld[4 + g] = &Bs[g * 512];
        }
    } else {
#pragma unroll
        for (int g = 0; g < 6; ++g) {
            sp[g] = Wbase + (size_t)(nt * 128 + (g + 2) * 16 + r16) * H_DIM + sc;
            ld[g] = &Bs[(g + 2) * 512];
        }
    }

    const int wn = wave << 6;
    const int lr = lane & 15;
    const int lq = lane >> 4;

    f32x4 acc[4][4];
#pragma unroll
    for (int mi = 0; mi < 4; ++mi)
#pragma unroll
        for (int ni = 0; ni < 4; ++ni)
            acc[mi][ni] = (f32x4){0.f, 0.f, 0.f, 0.f};

    for (int k0 = 0; k0 < H_DIM; k0 += 32) {
        __syncthreads();                 // prior ds_reads done before overwrite
#pragma unroll
        for (int g = 0; g < 6; ++g)
            gload16(sp[g] + k0, ld[g]);
        __syncthreads();                 // loads landed (vmcnt drained at barrier)

        short8 af[4], bf[4];
#pragma unroll
        for (int mi = 0; mi < 4; ++mi)
            af[mi] = *(const short8*)&As[(mi * 16 + lr) * 32 + lq * 8];
#pragma unroll
        for (int ni = 0; ni < 4; ++ni)
            bf[ni] = *(const short8*)&Bs[(wn + ni * 16 + lr) * 32 + lq * 8];
#pragma unroll
        for (int mi = 0; mi < 4; ++mi)
#pragma unroll
            for (int ni = 0; ni < 4; ++ni)
                acc[mi][ni] = __builtin_amdgcn_mfma_f32_16x16x32_bf16(
                    af[mi], bf[ni], acc[mi][ni], 0, 0, 0);
    }

    // epilogue: gelu -> bf16 h
#pragma unroll
    for (int mi = 0; mi < 4; ++mi) {
#pragma unroll
        for (int r = 0; r < 4; ++r) {
            int m = mt * 64 + mi * 16 + lq * 4 + r;
            if (m < cnt) {
                ushort_t* hp = h + (size_t)(base + m) * HFF_DIM + nt * 128 + wn + lr;
#pragma unroll
                for (int ni = 0; ni < 4; ++ni)
                    hp[ni * 16] = f2b(gelu_tanh(acc[mi][ni][r]));
            }
        }
    }
}

// ---------------- GEMM2: out[tok] += gate * (h[row] . W2b[e]^T) ----------------
__global__ __launch_bounds__(128) void gemm2_kernel(
        const ushort_t* __restrict__ h, const ushort_t* __restrict__ W2b,
        const int* __restrict__ count, const int* __restrict__ token_id,
        const float* __restrict__ gate, float* __restrict__ out) {
    const int wg  = blockIdx.x;
    const int swz = (wg & 7) * (G2_BLOCKS / 8) + (wg >> 3);
    const int e   = swz >> 9;           // 64 mt * 8 nt = 512 per expert
    const int rem = swz & 511;
    const int mt  = rem >> 3;
    const int nt  = rem & 7;

    const int cnt = count[e];
    if (mt * 64 >= cnt) return;
    int base = 0;
    for (int i = 0; i < e; ++i) base += count[i];

    __shared__ __align__(16) ushort_t As[64 * 32];
    __shared__ __align__(16) ushort_t Bs[128 * 32];

    const int tid = threadIdx.x;
    const int lane = tid & 63;
    const int wave = tid >> 6;

    const int r16 = lane >> 2;
    const int sc  = (lane & 3) << 3;

    const ushort_t* sp[6];
    ushort_t* ld[6];
    const ushort_t* Wbase = W2b + (size_t)e * H_DIM * HFF_DIM;
    if (wave == 0) {
#pragma unroll
        for (int g = 0; g < 4; ++g) {
            int ra = mt * 64 + g * 16 + r16;
            if (ra >= cnt) ra = cnt - 1;
            sp[g] = h + (size_t)(base + ra) * HFF_DIM + sc;
            ld[g] = &As[g * 512];
        }
#pragma unroll
        for (int g = 0; g < 2; ++g) {
            sp[4 + g] = Wbase + (size_t)(nt * 128 + g * 16 + r16) * HFF_DIM + sc;
            ld[4 + g] = &Bs[g * 512];
        }
    } else {
#pragma unroll
        for (int g = 0; g < 6; ++g) {
            sp[g] = Wbase + (size_t)(nt * 128 + (g + 2) * 16 + r16) * HFF_DIM + sc;
            ld[g] = &Bs[(g + 2) * 512];
        }
    }

    const int wn = wave << 6;
    const int lr = lane & 15;
    const int lq = lane >> 4;

    f32x4 acc[4][4];
#pragma unroll
    for (int mi = 0; mi < 4; ++mi)
#pragma unroll
        for (int ni = 0; ni < 4; ++ni)
            acc[mi][ni] = (f32x4){0.f, 0.f, 0.f, 0.f};

    for (int k0 = 0; k0 < HFF_DIM; k0 += 32) {
        __syncthreads();
#pragma unroll
        for (int g = 0; g < 6; ++g)
            gload16(sp[g] + k0, ld[g]);
        __syncthreads();

        short8 af[4], bf[4];
#pragma unroll
        for (int mi = 0; mi < 4; ++mi)
            af[mi] = *(const short8*)&As[(mi * 16 + lr) * 32 + lq * 8];
#pragma unroll
        for (int ni = 0; ni < 4; ++ni)
            bf[ni] = *(const short8*)&Bs[(wn + ni * 16 + lr) * 32 + lq * 8];
#pragma unroll
        for (int mi = 0; mi < 4; ++mi)
#pragma unroll
            for (int ni = 0; ni < 4; ++ni)
                acc[mi][ni] = __builtin_amdgcn_mfma_f32_16x16x32_bf16(
                    af[mi], bf[ni], acc[mi][ni], 0, 0, 0);
    }

    // epilogue: scale by gate, scatter-add into out
#pragma unroll
    for (int mi = 0; mi < 4; ++mi) {
#pragma unroll
        for (int r = 0; r < 4; ++r) {
            int m = mt * 64 + mi * 16 + lq * 4 + r;
            if (m < cnt) {
                int tok = token_id[e * TOKENS + m];
                float g = gate[e * TOKENS + m];
                float* op = out + (size_t)tok * H_DIM + nt * 128 + wn + lr;
#pragma unroll
                for (int ni = 0; ni < 4; ++ni)
                    atomicAdd(&op[ni * 16], g * acc[mi][ni][r]);
            }
        }
    }
}

extern "C" void kernel_launch(void* const* d_in, const int* in_sizes, int n_in,
                              void* d_out, int out_size, void* d_ws, size_t ws_size,
                              hipStream_t stream) {
    const float* x     = (const float*)d_in[0];
    const float* probs = (const float*)d_in[1];
    const int*   idx   = (const int*)d_in[2];
    const float* W1    = (const float*)d_in[3];
    const float* W2    = (const float*)d_in[4];
    float* out = (float*)d_out;

    char* ws = (char*)d_ws;
    int*      count    = (int*)ws;                               // 8 ints
    int*      token_id = (int*)(ws + 4096);                      // 8*4096 ints (128 KB)
    float*    gate     = (float*)(ws + 4096 + 8 * TOKENS * 4);   // 128 KB
    ushort_t* xb       = (ushort_t*)(ws + ((size_t)1 << 20));    // 8 MB
    ushort_t* W1b      = (ushort_t*)(ws + ((size_t)9 << 20));    // 64 MB

    // overlap path needs W1b + W2b live simultaneously (201 MB total);
    // fall back to serial shared-buffer layout if workspace is smaller.
    const bool overlap = ws_size >= ((size_t)201 << 20);
    ushort_t* W2b = overlap ? (ushort_t*)(ws + ((size_t)73 << 20)) : W1b;
    ushort_t* h   = overlap ? (ushort_t*)(ws + ((size_t)137 << 20))
                            : (ushort_t*)(ws + ((size_t)73 << 20));

    hipMemsetAsync(count, 0, 64, stream);
    hipMemsetAsync(out, 0, (size_t)out_size * sizeof(float), stream);

    // x-cvt + routing + W1-cvt, one BW-bound launch
    prep_kernel<<<XCVT_BLOCKS + W1CVT_BLOCKS, 256, 0, stream>>>(
        probs, idx, x, xb, W1, W1b, count, token_id, gate);

    if (overlap) {
        gemm1_kernel<<<G1_BLOCKS + W2CVT_BLOCKS, 128, 0, stream>>>(
            xb, W1b, count, token_id, h, W2, W2b);
    } else {
        gemm1_kernel<<<G1_BLOCKS, 128, 0, stream>>>(
            xb, W1b, count, token_id, h, W2, W2b);   // no cvt blocks
        int n8 = NEXP * H_DIM * HFF_DIM / 8;
        cvt_kernel<<<(n8 + 255) / 256, 256, 0, stream>>>(W2, W2b, n8);
    }

    gemm2_kernel<<<G2_BLOCKS, 128, 0, stream>>>(h, W2b, count, token_id, gate, out);
}